// Round 10
// baseline (590.892 us; speedup 1.0000x reference)
//
#include <hip/hip_runtime.h>
#include <cstdint>
#include <cstddef>

#define EE        800000
#define NC        100000
#define NM        50000
#define ND        10000
#define NSLOTS    320000

// relation order: 0=c->m, 1=m->d, 2=c->d, 3=m->c, 4=d->m, 5=d->c
#define SB0 0
#define SB1 50000
#define SB2 60000
#define SB3 70000
#define SB4 170000
#define SB5 220000

// y_all row offsets per relation (src-transformed tables)
#define R0 0
#define R1 100000
#define R2 150000
#define R3 250000
#define R4 300000
#define R5 310000

// buckets: 400/relation; spb: {125,25,25,250,125,250}
#define NB 2400
#define EPB 4096
#define EBL 196
#define PPB 4096
#define PBL 196
#define BCAP 4096

typedef _Float16 f16x8 __attribute__((ext_vector_type(8)));
typedef float f32x4 __attribute__((ext_vector_type(4)));
typedef float f32x2 __attribute__((ext_vector_type(2)));

__device__ __forceinline__ void bucket_split(int rel, int d, int& lb, int& dl) {
    switch (rel) {
        case 0: case 4: lb = d / 125; dl = d - lb * 125; break;
        case 1: case 2: lb = d / 25;  dl = d - lb * 25;  break;
        default:        lb = d / 250; dl = d - lb * 250; break;
    }
}

__device__ __forceinline__ unsigned f2bf(float f) {   // RNE
    unsigned b = __float_as_uint(f);
    return (b + 0x7FFFu + ((b >> 16) & 1u)) >> 16;
}

// ---- merged: weight prep (blocks 0..191) + bucket hist (blocks 192..1367) ----
// bhist is pre-zeroed by hipMemsetAsync BEFORE this launch (no in-kernel zeroing:
// zero+atomicAdd in one dispatch is a block-order race, learned round 5).
// type order t: 0=m (dst of rels 0,4), 1=d (1,2), 2=c (3,5); rmap {1,2,0}
__global__ __launch_bounds__(256) void cvt_hist_k(
    const float* __restrict__ W1l, const float* __restrict__ W2l,
    const float* __restrict__ W1r, const float* __restrict__ W2r,
    const float* __restrict__ Wres, const float* __restrict__ b1,
    const float* __restrict__ b2, const float* __restrict__ bres,
    _Float16* __restrict__ Wt1, _Float16* __restrict__ Wt2,
    _Float16* __restrict__ Wz1t, _Float16* __restrict__ Wz2t,
    _Float16* __restrict__ Wrest, float* __restrict__ bz1, float* __restrict__ bz2,
    int* __restrict__ bhist,
    const int* __restrict__ d0, const int* __restrict__ d1, const int* __restrict__ d2,
    const int* __restrict__ d3, const int* __restrict__ d4, const int* __restrict__ d5)
{
    __shared__ int hl[400];
    int blk = blockIdx.x;
    int tid = threadIdx.x;
    if (blk < 192) {
        const int raT[3] = {0, 1, 3}, rbT[3] = {4, 2, 5}, rmT[3] = {1, 2, 0};
        int i = blk * 256 + tid;
        if (i < 6 * 128 * 64) {
            int r = i >> 13, rem = i & 8191, k = rem >> 6, n = rem & 63;
            Wt1[(size_t)r * 8192 + (size_t)n * 128 + k] = (_Float16)W1l[i];
        }
        if (i < 6 * 64 * 64) {
            int r = i >> 12, rem = i & 4095, k = rem >> 6, n = rem & 63;
            Wt2[(size_t)r * 4096 + (size_t)n * 64 + k] = (_Float16)W2l[i];
        }
        if (i < 3 * 8192) {
            int t = i >> 13, rem = i & 8191, n = rem >> 7, k = rem & 127;
            float v = 0.5f * (W1r[(size_t)raT[t] * 8192 + k * 64 + n] +
                              W1r[(size_t)rbT[t] * 8192 + k * 64 + n]);
            Wz1t[i] = (_Float16)v;
        }
        if (i < 3 * 4096) {
            int t = i >> 12, rem = i & 4095, n = rem >> 6, k = rem & 63;
            float v = 0.5f * (W2r[(size_t)raT[t] * 4096 + k * 64 + n] +
                              W2r[(size_t)rbT[t] * 4096 + k * 64 + n]);
            Wz2t[i] = (_Float16)v;
        }
        if (i < 3 * 8192) {
            int t = i >> 13, rem = i & 8191, n = rem >> 7, k = rem & 127;
            Wrest[i] = (_Float16)Wres[(size_t)rmT[t] * 8192 + k * 64 + n];
        }
        if (i < 192) {
            int t = i >> 6, n = i & 63;
            bz1[i] = 0.5f * (b1[raT[t] * 64 + n] + b1[rbT[t] * 64 + n]);
            bz2[i] = 0.5f * (b2[raT[t] * 64 + n] + b2[rbT[t] * 64 + n]) + bres[rmT[t] * 64 + n];
        }
        return;
    }
    int hb = blk - 192;
    int rel = hb / EBL;
    int chunk = hb - rel * EBL;
    const int* dst;
    switch (rel) {
        case 0: dst = d0; break; case 1: dst = d1; break; case 2: dst = d2; break;
        case 3: dst = d3; break; case 4: dst = d4; break; default: dst = d5; break;
    }
    for (int i = tid; i < 400; i += 256) hl[i] = 0;
    __syncthreads();
    int e0 = chunk * EPB;
#pragma unroll
    for (int t = 0; t < EPB / 256; ++t) {
        int e = e0 + t * 256 + tid;
        if (e < EE) {
            int lb, dl;
            bucket_split(rel, dst[e], lb, dl);
            atomicAdd(&hl[lb], 1);
        }
    }
    __syncthreads();
    for (int i = tid; i < 400; i += 256) {
        int v = hl[i];
        if (v) atomicAdd(&bhist[rel * 400 + i], v);
    }
}

__global__ __launch_bounds__(256) void bucket_scan_k(const int* __restrict__ bhist,
    int* __restrict__ bOff, int* __restrict__ bCur, int* __restrict__ off)
{
    __shared__ int lds[256];
    int tid = threadIdx.x;
    int v[10];
    int tot = 0;
#pragma unroll
    for (int t = 0; t < 10; ++t) {
        int idx = tid * 10 + t;
        int x = (idx < NB) ? bhist[idx] : 0;
        v[t] = tot;
        tot += x;
    }
    lds[tid] = tot;
    __syncthreads();
    for (int o = 1; o < 256; o <<= 1) {
        int x = 0;
        if (tid >= o) x = lds[tid - o];
        __syncthreads();
        lds[tid] += x;
        __syncthreads();
    }
    int excl = lds[tid] - tot;
#pragma unroll
    for (int t = 0; t < 10; ++t) {
        int idx = tid * 10 + t;
        if (idx < NB) {
            int val = excl + v[t];
            bOff[idx] = val;
            bCur[idx] = val;
        }
    }
    if (tid == 255) {
        bOff[NB] = lds[255];
        off[NSLOTS] = lds[255];
    }
}

// ---- standalone partition (512 threads, 8 dependent-load iters/pass):
// in-LDS counting sort -> coalesced bArr writes (round-8's proven fix for the
// 116 MB partial-line write amplification).
__global__ __launch_bounds__(512) void partition_k(
    const int* __restrict__ s0, const int* __restrict__ d0,
    const int* __restrict__ s1, const int* __restrict__ d1,
    const int* __restrict__ s2, const int* __restrict__ d2,
    const int* __restrict__ s3, const int* __restrict__ d3,
    const int* __restrict__ s4, const int* __restrict__ d4,
    const int* __restrict__ s5, const int* __restrict__ d5,
    int* __restrict__ bCur, int* __restrict__ bArr)
{
    __shared__ int hist[400];                 // counts, then rank counters
    __shared__ int scan_[400];                // exclusive prefix (LDS positions)
    __shared__ int gb[400];                   // global bases
    __shared__ int sorted[PPB];               // payloads, bucket-sorted
    __shared__ unsigned short lbs16[PPB];     // bucket id per sorted pos
    int blk = blockIdx.x;
    int tid = threadIdx.x;
    int rel = blk / PBL;
    int chunk = blk - rel * PBL;
    const int* src; const int* dst;
    switch (rel) {
        case 0: src = s0; dst = d0; break;
        case 1: src = s1; dst = d1; break;
        case 2: src = s2; dst = d2; break;
        case 3: src = s3; dst = d3; break;
        case 4: src = s4; dst = d4; break;
        default: src = s5; dst = d5; break;
    }
    for (int i = tid; i < 400; i += 512) hist[i] = 0;
    __syncthreads();
    int e0 = chunk * PPB;
    int e1 = e0 + PPB; if (e1 > EE) e1 = EE;
    int m = e1 - e0;
    for (int i = tid; i < m; i += 512) {
        int lb, dl;
        bucket_split(rel, dst[e0 + i], lb, dl);
        atomicAdd(&hist[lb], 1);
    }
    __syncthreads();
    // wave 0: exclusive scan over 400 buckets (7 chunks of 64, shfl)
    if (tid < 64) {
        int carry = 0;
#pragma unroll
        for (int c = 0; c < 7; ++c) {
            int idx = c * 64 + tid;
            int orig = (idx < 400) ? hist[idx] : 0;
            int v = orig;
#pragma unroll
            for (int o = 1; o < 64; o <<= 1) {
                int u = __shfl_up(v, o);
                if (tid >= o) v += u;
            }
            if (idx < 400) scan_[idx] = carry + v - orig;
            carry += __shfl(v, 63);
        }
    }
    // concurrently: per-bucket global reservation (reads hist only)
    for (int i = tid; i < 400; i += 512) {
        int c = hist[i];
        gb[i] = c ? atomicAdd(&bCur[rel * 400 + i], c) : 0;
    }
    __syncthreads();
    for (int i = tid; i < 400; i += 512) hist[i] = 0;   // rank counters
    __syncthreads();
    for (int i = tid; i < m; i += 512) {
        int d = dst[e0 + i];          // L2-hot re-read
        int s = src[e0 + i];
        int lb, dl;
        bucket_split(rel, d, lb, dl);
        int r = atomicAdd(&hist[lb], 1);
        int pos = scan_[lb] + r;
        sorted[pos] = (dl << 17) | s;
        lbs16[pos] = (unsigned short)lb;
    }
    __syncthreads();
    // coalesced write-out: consecutive i -> consecutive global addresses
    for (int i = tid; i < m; i += 512) {
        int lb = lbs16[i];
        bArr[gb[lb] + i - scan_[lb]] = sorted[i];
    }
}

// ---- merged: bucket_build (blocks 0..2399) + fused L1 (blocks 2400..4901) ----
// build and fused1 are data-independent; union LDS 19.5 KB -> 8 blocks/CU.
// csr payload = src byte-offset (src<<7).  bArr ALIASES csr: whole bucket
// (<= BCAP; stat max ~2225) staged into LDS before any csr write.
__global__ __launch_bounds__(256) void build_fused1_k(
    const int* __restrict__ bArr, const int* __restrict__ bOff,
    int* __restrict__ off, int* __restrict__ csr,
    const float* __restrict__ fc, const float* __restrict__ fm, const float* __restrict__ fd,
    const _Float16* __restrict__ Wt1, const _Float16* __restrict__ Wz1t,
    const float* __restrict__ bz1,
    unsigned short* __restrict__ y,
    float* __restrict__ hc, float* __restrict__ hm, float* __restrict__ hd)
{
    __shared__ __align__(16) char smem[19456];
    int blk = blockIdx.x;
    int tid = threadIdx.x;
    if (blk < NB) {
        int* cnt = (int*)smem;            // 256
        int* sc = cnt + 256;              // 256
        int* cur = sc + 256;              // 256
        int* stage = cur + 256;           // 4096
        int b = blk;
        int r = b / 400;
        int lb = b - r * 400;
        int spb, sbase;
        switch (r) {
            case 0: spb = 125; sbase = SB0; break;
            case 1: spb = 25;  sbase = SB1; break;
            case 2: spb = 25;  sbase = SB2; break;
            case 3: spb = 250; sbase = SB3; break;
            case 4: spb = 125; sbase = SB4; break;
            default: spb = 250; sbase = SB5; break;
        }
        int slot0 = lb * spb;
        int e0 = bOff[b], e1 = bOff[b + 1];
        int m = e1 - e0;
        int ms = m < BCAP ? m : BCAP;

        cnt[tid] = 0;
        __syncthreads();
        for (int i = tid; i < ms; i += 256) {
            int p = bArr[e0 + i];
            stage[i] = p;
            atomicAdd(&cnt[p >> 17], 1);
        }
        __syncthreads();
        int x = cnt[tid];
        sc[tid] = x;
        __syncthreads();
        for (int o = 1; o < 256; o <<= 1) {
            int yv = 0;
            if (tid >= o) yv = sc[tid - o];
            __syncthreads();
            sc[tid] += yv;
            __syncthreads();
        }
        int excl = sc[tid] - x;
        cur[tid] = excl;
        if (tid < spb) off[sbase + slot0 + tid] = e0 + excl;
        __syncthreads();
        for (int i = tid; i < ms; i += 256) {
            int p = stage[i];
            int pos = atomicAdd(&cur[p >> 17], 1);
            csr[e0 + pos] = (p & 0x1FFFF) << 7;
        }
        return;
    }
    // ---- fused1: per 64-row tile of type t, stage x once (f16, LDS):
    //   wave0: y[ra]=x@Wt1[ra]  wave1: y[rb]=x@Wt1[rb]  wave2/3: h=x@Wz1t[t]+bz1[t]
    _Float16* xs = (_Float16*)smem;   // [64][136]
    int b = blk - NB;
    int t, lb;
    if (b < 782)      { t = 0; lb = b; }
    else if (b < 939) { t = 1; lb = b - 782; }
    else              { t = 2; lb = b - 939; }
    const float* x; int n; float* zo; int ra, rb, roA, roB;
    switch (t) {
        case 0: x = fm; n = NM; zo = hm; ra = 1; rb = 3; roA = R1; roB = R3; break;
        case 1: x = fd; n = ND; zo = hd; ra = 4; rb = 5; roA = R4; roB = R5; break;
        default: x = fc; n = NC; zo = hc; ra = 0; rb = 2; roA = R0; roB = R2; break;
    }
    int node0 = lb * 64;
    for (int idx = tid; idx < 64 * 16; idx += 256) {
        int nn = idx >> 4, c8 = idx & 15;
        int g = node0 + nn;
        float4 u0 = make_float4(0.f, 0.f, 0.f, 0.f), u1 = u0;
        if (g < n) {
            const float4* p = (const float4*)(x + (size_t)g * 128 + c8 * 8);
            u0 = p[0]; u1 = p[1];
        }
        f16x8 v;
        v[0] = (_Float16)u0.x; v[1] = (_Float16)u0.y; v[2] = (_Float16)u0.z; v[3] = (_Float16)u0.w;
        v[4] = (_Float16)u1.x; v[5] = (_Float16)u1.y; v[6] = (_Float16)u1.z; v[7] = (_Float16)u1.w;
        *(f16x8*)(xs + nn * 136 + c8 * 8) = v;
    }
    __syncthreads();
    int lane = tid & 63, wv = tid >> 6;
    int lr = lane & 15, lg = lane >> 4;
    if (wv < 2) {
        int rel = wv ? rb : ra;
        int ro  = wv ? roB : roA;
        const _Float16* W = Wt1 + (size_t)rel * 8192;
        unsigned short* yo = y + (size_t)ro * 64;
        f16x8 bf[4][4];
#pragma unroll
        for (int kt = 0; kt < 4; ++kt)
#pragma unroll
            for (int nt = 0; nt < 4; ++nt)
                bf[kt][nt] = *(const f16x8*)(W + (size_t)(nt * 16 + lr) * 128 + kt * 32 + lg * 8);
#pragma unroll
        for (int rt = 0; rt < 4; ++rt) {
            f32x4 acc[4];
#pragma unroll
            for (int nt = 0; nt < 4; ++nt) { acc[nt][0] = 0.f; acc[nt][1] = 0.f; acc[nt][2] = 0.f; acc[nt][3] = 0.f; }
            const _Float16* xrow = xs + (rt * 16 + lr) * 136;
#pragma unroll
            for (int kt = 0; kt < 4; ++kt) {
                f16x8 af = *(const f16x8*)(xrow + kt * 32 + lg * 8);
#pragma unroll
                for (int nt = 0; nt < 4; ++nt)
                    acc[nt] = __builtin_amdgcn_mfma_f32_16x16x32_f16(af, bf[kt][nt], acc[nt], 0, 0, 0);
            }
            int orow = node0 + rt * 16 + lg * 4;
#pragma unroll
            for (int rg = 0; rg < 4; ++rg) {
                int gg = orow + rg;
                if (gg < n) {
                    unsigned short* yr = yo + (size_t)gg * 64 + lr;
#pragma unroll
                    for (int nt = 0; nt < 4; ++nt)
                        yr[nt * 16] = (unsigned short)f2bf(acc[nt][rg]);
                }
            }
        }
    } else {
        const _Float16* W = Wz1t + (size_t)t * 8192;
        const float* bz = bz1 + t * 64;
        f16x8 bf[4][4];
#pragma unroll
        for (int kt = 0; kt < 4; ++kt)
#pragma unroll
            for (int nt = 0; nt < 4; ++nt)
                bf[kt][nt] = *(const f16x8*)(W + (size_t)(nt * 16 + lr) * 128 + kt * 32 + lg * 8);
        int rbase = (wv - 2) * 32;
#pragma unroll
        for (int rt = 0; rt < 2; ++rt) {
            f32x4 acc[4];
#pragma unroll
            for (int nt = 0; nt < 4; ++nt) {
                float bv = bz[nt * 16 + lr];
                acc[nt][0] = bv; acc[nt][1] = bv; acc[nt][2] = bv; acc[nt][3] = bv;
            }
            const _Float16* xrow = xs + (rbase + rt * 16 + lr) * 136;
#pragma unroll
            for (int kt = 0; kt < 4; ++kt) {
                f16x8 af = *(const f16x8*)(xrow + kt * 32 + lg * 8);
#pragma unroll
                for (int nt = 0; nt < 4; ++nt)
                    acc[nt] = __builtin_amdgcn_mfma_f32_16x16x32_f16(af, bf[kt][nt], acc[nt], 0, 0, 0);
            }
            int orow = node0 + rbase + rt * 16 + lg * 4;
#pragma unroll
            for (int rg = 0; rg < 4; ++rg) {
                int gg = orow + rg;
                if (gg < n) {
                    float* zr = zo + (size_t)gg * 64 + lr;
#pragma unroll
                    for (int nt = 0; nt < 4; ++nt)
                        zr[nt * 16] = acc[nt][rg];
                }
            }
        }
    }
}

// ---- fused L2: per 64-row tile of type t, stage h + x once (f16, LDS):
//   wave0: y[ra] = h@Wt2[ra]   wave1: y[rb] = h@Wt2[rb]
//   wave2/3: out = h@Wz2t[t] + x@Wrest[t] + bz2[t]
__global__ __launch_bounds__(256) void fused2_k(
    const float* __restrict__ hc, const float* __restrict__ hm, const float* __restrict__ hd,
    const float* __restrict__ xc, const float* __restrict__ xm, const float* __restrict__ xd,
    const _Float16* __restrict__ Wt2, const _Float16* __restrict__ Wz2t,
    const _Float16* __restrict__ Wrest, const float* __restrict__ bz2,
    unsigned short* __restrict__ y,
    float* __restrict__ oc, float* __restrict__ om, float* __restrict__ od)
{
    int b = blockIdx.x;
    int t, lb;
    if (b < 782)      { t = 0; lb = b; }
    else if (b < 939) { t = 1; lb = b - 782; }
    else              { t = 2; lb = b - 939; }
    const float *h, *x; int n; float* zo; int ra, rb, roA, roB;
    switch (t) {
        case 0: h = hm; x = xm; n = NM; zo = om; ra = 1; rb = 3; roA = R1; roB = R3; break;
        case 1: h = hd; x = xd; n = ND; zo = od; ra = 4; rb = 5; roA = R4; roB = R5; break;
        default: h = hc; x = xc; n = NC; zo = oc; ra = 0; rb = 2; roA = R0; roB = R2; break;
    }
    __shared__ _Float16 hs[64 * 72];
    __shared__ _Float16 xs[64 * 136];
    int tid = threadIdx.x;
    int node0 = lb * 64;
    for (int idx = tid; idx < 64 * 8; idx += 256) {
        int nn = idx >> 3, c8 = idx & 7;
        int g = node0 + nn;
        float4 u0 = make_float4(0.f, 0.f, 0.f, 0.f), u1 = u0;
        if (g < n) {
            const float4* p = (const float4*)(h + (size_t)g * 64 + c8 * 8);
            u0 = p[0]; u1 = p[1];
        }
        f16x8 v;
        v[0] = (_Float16)u0.x; v[1] = (_Float16)u0.y; v[2] = (_Float16)u0.z; v[3] = (_Float16)u0.w;
        v[4] = (_Float16)u1.x; v[5] = (_Float16)u1.y; v[6] = (_Float16)u1.z; v[7] = (_Float16)u1.w;
        *(f16x8*)(hs + nn * 72 + c8 * 8) = v;
    }
    for (int idx = tid; idx < 64 * 16; idx += 256) {
        int nn = idx >> 4, c8 = idx & 15;
        int g = node0 + nn;
        float4 u0 = make_float4(0.f, 0.f, 0.f, 0.f), u1 = u0;
        if (g < n) {
            const float4* p = (const float4*)(x + (size_t)g * 128 + c8 * 8);
            u0 = p[0]; u1 = p[1];
        }
        f16x8 v;
        v[0] = (_Float16)u0.x; v[1] = (_Float16)u0.y; v[2] = (_Float16)u0.z; v[3] = (_Float16)u0.w;
        v[4] = (_Float16)u1.x; v[5] = (_Float16)u1.y; v[6] = (_Float16)u1.z; v[7] = (_Float16)u1.w;
        *(f16x8*)(xs + nn * 136 + c8 * 8) = v;
    }
    __syncthreads();
    int lane = tid & 63, wv = tid >> 6;
    int lr = lane & 15, lg = lane >> 4;
    if (wv < 2) {
        int rel = wv ? rb : ra;
        int ro  = wv ? roB : roA;
        const _Float16* W = Wt2 + (size_t)rel * 4096;
        unsigned short* yo = y + (size_t)ro * 64;
        f16x8 bf[2][4];
#pragma unroll
        for (int kt = 0; kt < 2; ++kt)
#pragma unroll
            for (int nt = 0; nt < 4; ++nt)
                bf[kt][nt] = *(const f16x8*)(W + (size_t)(nt * 16 + lr) * 64 + kt * 32 + lg * 8);
#pragma unroll
        for (int rt = 0; rt < 4; ++rt) {
            f32x4 acc[4];
#pragma unroll
            for (int nt = 0; nt < 4; ++nt) { acc[nt][0] = 0.f; acc[nt][1] = 0.f; acc[nt][2] = 0.f; acc[nt][3] = 0.f; }
            const _Float16* hrow = hs + (rt * 16 + lr) * 72;
#pragma unroll
            for (int kt = 0; kt < 2; ++kt) {
                f16x8 af = *(const f16x8*)(hrow + kt * 32 + lg * 8);
#pragma unroll
                for (int nt = 0; nt < 4; ++nt)
                    acc[nt] = __builtin_amdgcn_mfma_f32_16x16x32_f16(af, bf[kt][nt], acc[nt], 0, 0, 0);
            }
            int orow = node0 + rt * 16 + lg * 4;
#pragma unroll
            for (int rg = 0; rg < 4; ++rg) {
                int gg = orow + rg;
                if (gg < n) {
                    unsigned short* yr = yo + (size_t)gg * 64 + lr;
#pragma unroll
                    for (int nt = 0; nt < 4; ++nt)
                        yr[nt * 16] = (unsigned short)f2bf(acc[nt][rg]);
                }
            }
        }
    } else {
        const _Float16* Wh = Wz2t + (size_t)t * 4096;
        const _Float16* Wx = Wrest + (size_t)t * 8192;
        const float* bz = bz2 + t * 64;
        f16x8 bfh[2][4];
#pragma unroll
        for (int kt = 0; kt < 2; ++kt)
#pragma unroll
            for (int nt = 0; nt < 4; ++nt)
                bfh[kt][nt] = *(const f16x8*)(Wh + (size_t)(nt * 16 + lr) * 64 + kt * 32 + lg * 8);
        f16x8 bfx[4][4];
#pragma unroll
        for (int kt = 0; kt < 4; ++kt)
#pragma unroll
            for (int nt = 0; nt < 4; ++nt)
                bfx[kt][nt] = *(const f16x8*)(Wx + (size_t)(nt * 16 + lr) * 128 + kt * 32 + lg * 8);
        int rbase = (wv - 2) * 32;
#pragma unroll
        for (int rt = 0; rt < 2; ++rt) {
            f32x4 acc[4];
#pragma unroll
            for (int nt = 0; nt < 4; ++nt) {
                float bv = bz[nt * 16 + lr];
                acc[nt][0] = bv; acc[nt][1] = bv; acc[nt][2] = bv; acc[nt][3] = bv;
            }
            const _Float16* hrow = hs + (rbase + rt * 16 + lr) * 72;
            const _Float16* xrow = xs + (rbase + rt * 16 + lr) * 136;
#pragma unroll
            for (int kt = 0; kt < 2; ++kt) {
                f16x8 af = *(const f16x8*)(hrow + kt * 32 + lg * 8);
#pragma unroll
                for (int nt = 0; nt < 4; ++nt)
                    acc[nt] = __builtin_amdgcn_mfma_f32_16x16x32_f16(af, bfh[kt][nt], acc[nt], 0, 0, 0);
            }
#pragma unroll
            for (int kt = 0; kt < 4; ++kt) {
                f16x8 af = *(const f16x8*)(xrow + kt * 32 + lg * 8);
#pragma unroll
                for (int nt = 0; nt < 4; ++nt)
                    acc[nt] = __builtin_amdgcn_mfma_f32_16x16x32_f16(af, bfx[kt][nt], acc[nt], 0, 0, 0);
            }
            int orow = node0 + rbase + rt * 16 + lg * 4;
#pragma unroll
            for (int rg = 0; rg < 4; ++rg) {
                int gg = orow + rg;
                if (gg < n) {
                    float* zr = zo + (size_t)gg * 64 + lr;
#pragma unroll
                    for (int nt = 0; nt < 4; ++nt)
                        zr[nt * 16] = acc[nt][rg];
                }
            }
        }
    }
}

// packed bf16x4 accumulate (8 B): 4 cvt ops + 2 v_pk_add_f32
__device__ __forceinline__ void acc_pk2(f32x2* a, uint2 v) {
    f32x2 t0, t1;
    t0[0] = __uint_as_float(v.x << 16); t0[1] = __uint_as_float(v.x & 0xFFFF0000u);
    t1[0] = __uint_as_float(v.y << 16); t1[1] = __uint_as_float(v.y & 0xFFFF0000u);
    a[0] += t0; a[1] += t1;
}

// fused aggregate (bf16 y, csr = byte offsets):
//   io[wid] = post(0.5*(mean(y1[csr])+mean(y2[csr])) + io[wid])
// round-10 geometry: wave = 4 groups x 16 lanes (lane loads 8 B of the 128-B row).
// Rationale: mean degree 8-16 for m/c types left 8-lane groups with 1-2 edges while
// the 8-acc x 3-round shfl reduction (48 wave-ops/dest) dominated VALU. 16-lane
// groups double stream depth and halve the reduction (4 acc x 2 rounds).
// Index prefetch UNCLAMPED (OOB reads land in ws slack, values provably unused).
template<bool RELU, bool NORM>
__global__ __launch_bounds__(256) void agg_all_k(
    const unsigned short* __restrict__ y, const int* __restrict__ off,
    const int* __restrict__ csr,
    float* __restrict__ ioc, float* __restrict__ iom, float* __restrict__ iod)
{
    int w = blockIdx.x * 4 + (threadIdx.x >> 6);
    int t, wid;
    if (w < NM) { t = 0; wid = w; }
    else if (w < NM + ND) { t = 1; wid = w - NM; }
    else { t = 2; wid = w - NM - ND; }
    const int *o1, *o2; const unsigned short *y1, *y2; float* io;
    switch (t) {
        case 0: o1 = off + SB0; o2 = off + SB4; y1 = y + (size_t)R0 * 64; y2 = y + (size_t)R4 * 64; io = iom; break;
        case 1: o1 = off + SB1; o2 = off + SB2; y1 = y + (size_t)R1 * 64; y2 = y + (size_t)R2 * 64; io = iod; break;
        default: o1 = off + SB3; o2 = off + SB5; y1 = y + (size_t)R3 * 64; y2 = y + (size_t)R5 * 64; io = ioc; break;
    }
    int lane = threadIdx.x & 63;
    int g = lane >> 4, ql = lane & 15;   // group (0..3), sixteenth-lane
    int qoff = ql * 8;
    f32x2 acc[2];
#pragma unroll
    for (int j = 0; j < 2; ++j) { acc[j][0] = 0.f; acc[j][1] = 0.f; }
    {
        const char* yb = (const char*)y1 + qoff;
        int e0 = o1[wid], e1 = o1[wid + 1];
        f32x2 a[2];
#pragma unroll
        for (int j = 0; j < 2; ++j) { a[j][0] = 0.f; a[j][1] = 0.f; }
        int e = e0 + g;
        int i0 = 0, i1 = 0;
        if (e < e1) i0 = csr[e];
        if (e + 4 < e1) i1 = csr[e + 4];
        for (; e + 4 < e1; e += 8) {
            int p0 = csr[e + 8];
            int p1 = csr[e + 12];
            uint2 vA = *(const uint2*)(yb + (unsigned)i0);
            uint2 vB = *(const uint2*)(yb + (unsigned)i1);
            acc_pk2(a, vA);
            acc_pk2(a, vB);
            i0 = p0; i1 = p1;
        }
        if (e < e1) {
            uint2 v = *(const uint2*)(yb + (unsigned)i0);
            acc_pk2(a, v);
        }
        float inv = 1.f / fmaxf((float)(e1 - e0), 1.f);
        f32x2 iv; iv[0] = inv; iv[1] = inv;
#pragma unroll
        for (int j = 0; j < 2; ++j) acc[j] += a[j] * iv;
    }
    {
        const char* yb = (const char*)y2 + qoff;
        int e0 = o2[wid], e1 = o2[wid + 1];
        f32x2 a[2];
#pragma unroll
        for (int j = 0; j < 2; ++j) { a[j][0] = 0.f; a[j][1] = 0.f; }
        int e = e0 + g;
        int i0 = 0, i1 = 0;
        if (e < e1) i0 = csr[e];
        if (e + 4 < e1) i1 = csr[e + 4];
        for (; e + 4 < e1; e += 8) {
            int p0 = csr[e + 8];
            int p1 = csr[e + 12];
            uint2 vA = *(const uint2*)(yb + (unsigned)i0);
            uint2 vB = *(const uint2*)(yb + (unsigned)i1);
            acc_pk2(a, vA);
            acc_pk2(a, vB);
            i0 = p0; i1 = p1;
        }
        if (e < e1) {
            uint2 v = *(const uint2*)(yb + (unsigned)i0);
            acc_pk2(a, v);
        }
        float inv = 1.f / fmaxf((float)(e1 - e0), 1.f);
        f32x2 iv; iv[0] = inv; iv[1] = inv;
#pragma unroll
        for (int j = 0; j < 2; ++j) acc[j] += a[j] * iv;
    }
    // reduce across the 4 groups (component-wise, 2 shfl rounds)
#pragma unroll
    for (int j = 0; j < 2; ++j) {
#pragma unroll
        for (int c = 0; c < 2; ++c) {
            float v = acc[j][c];
            v += __shfl_xor(v, 16);
            v += __shfl_xor(v, 32);
            acc[j][c] = v;
        }
    }
    if (g == 0) {
        float* iorow = io + ((size_t)wid << 6) + ql * 4;
        float4 z = *((const float4*)iorow);
        float o[4];
        o[0] = 0.5f * acc[0][0] + z.x; o[1] = 0.5f * acc[0][1] + z.y;
        o[2] = 0.5f * acc[1][0] + z.z; o[3] = 0.5f * acc[1][1] + z.w;
        if (RELU) {
#pragma unroll
            for (int j = 0; j < 4; ++j) o[j] = fmaxf(o[j], 0.f);
        }
        if (NORM) {
            float ss = 0.f;
#pragma unroll
            for (int j = 0; j < 4; ++j) ss += o[j] * o[j];
            ss += __shfl_xor(ss, 1); ss += __shfl_xor(ss, 2);
            ss += __shfl_xor(ss, 4); ss += __shfl_xor(ss, 8);
            float r = 1.f / fmaxf(sqrtf(ss), 1e-12f);
#pragma unroll
            for (int j = 0; j < 4; ++j) o[j] *= r;
        }
        *((float4*)iorow) = make_float4(o[0], o[1], o[2], o[3]);
    }
}

extern "C" void kernel_launch(void* const* d_in, const int* in_sizes, int n_in,
                              void* d_out, int out_size, void* d_ws, size_t ws_size,
                              hipStream_t stream) {
    const float* x_c = (const float*)d_in[0];
    const float* x_m = (const float*)d_in[1];
    const float* x_d = (const float*)d_in[2];
    const int* src_cm = (const int*)d_in[3];
    const int* dst_cm = (const int*)d_in[4];
    const int* src_md = (const int*)d_in[5];
    const int* dst_md = (const int*)d_in[6];
    const int* src_cd = (const int*)d_in[7];
    const int* dst_cd = (const int*)d_in[8];
    const int* src_mc = (const int*)d_in[9];
    const int* dst_mc = (const int*)d_in[10];
    const int* src_dm = (const int*)d_in[11];
    const int* dst_dm = (const int*)d_in[12];
    const int* src_dc = (const int*)d_in[13];
    const int* dst_dc = (const int*)d_in[14];
    const float* W1l = (const float*)d_in[15];  // [6][128][64]
    const float* W1r = (const float*)d_in[16];
    const float* b1 = (const float*)d_in[17];   // [6][64]
    const float* W2l = (const float*)d_in[18];  // [6][64][64]
    const float* W2r = (const float*)d_in[19];
    const float* b2 = (const float*)d_in[20];
    const float* Wres = (const float*)d_in[21]; // [3][128][64]
    const float* bres = (const float*)d_in[22]; // [3][64]
    float* out = (float*)d_out;

    // workspace
    int* off = (int*)d_ws;                 // 320064
    int* csr = off + 320064;               // 4,800,000 (+24 slack ints into bhist OK)
    int* bArr = csr;                       // ALIAS: build stages whole bucket in LDS
    int* bhist = csr + 4800000;            // 2400
    int* bOff = bhist + 2400;              // 2404
    int* bCur = bOff + 2404;               // 2404
    float* h = (float*)(bCur + 2404);      // 160000*64 floats: [c|m|d]
    float* h_c = h;
    float* h_m = h_c + (size_t)NC * 64;
    float* h_d = h_m + (size_t)NM * 64;
    unsigned short* y = (unsigned short*)(h + (size_t)160000 * 64); // 320000*64 bf16
    _Float16* Wt1 = (_Float16*)(y + (size_t)320000 * 64);  // 6*64*128 f16
    _Float16* Wt2 = Wt1 + 6 * 64 * 128;                    // 6*64*64 f16
    _Float16* Wz1t = Wt2 + 6 * 64 * 64;                    // 3*64*128
    _Float16* Wz2t = Wz1t + 3 * 64 * 128;                  // 3*64*64
    _Float16* Wrest = Wz2t + 3 * 64 * 64;                  // 3*64*128
    float* bz1 = (float*)(Wrest + 3 * 64 * 128);           // 3*64
    float* bz2 = bz1 + 192;                                // 3*64

    float* out_c = out;
    float* out_m = out + (size_t)NC * 64;
    float* out_d = out_m + (size_t)NM * 64;

    // K0: zero bhist (stream-ordered BEFORE the hist kernel — block-order-safe)
    hipMemsetAsync(bhist, 0, NB * sizeof(int), stream);

    // K1: weight prep + bucket hist (independent, one launch)
    cvt_hist_k<<<192 + EBL * 6, 256, 0, stream>>>(
        W1l, W2l, W1r, W2r, Wres, b1, b2, bres,
        Wt1, Wt2, Wz1t, Wz2t, Wrest, bz1, bz2, bhist,
        dst_cm, dst_md, dst_cd, dst_mc, dst_dm, dst_dc);

    // K2: bucket scan
    bucket_scan_k<<<1, 256, 0, stream>>>(bhist, bOff, bCur, off);

    // K3: partition (512 thr, counting-sorted coalesced writes)
    partition_k<<<6 * PBL, 512, 0, stream>>>(
        src_cm, dst_cm, src_md, dst_md, src_cd, dst_cd,
        src_mc, dst_mc, src_dm, dst_dm, src_dc, dst_dc,
        bCur, bArr);

    // K4: bucket_build (2400 blocks, first) overlapped with fused L1 (2502 blocks)
    build_fused1_k<<<NB + 2502, 256, 0, stream>>>(
        bArr, bOff, off, csr,
        x_c, x_m, x_d, Wt1, Wz1t, bz1, y, h_c, h_m, h_d);

    // K5: aggregate layer 1
    agg_all_k<true, false><<<40000, 256, 0, stream>>>(y, off, csr, h_c, h_m, h_d);

    // K6: fused L2 GEMMs
    fused2_k<<<2502, 256, 0, stream>>>(h_c, h_m, h_d, x_c, x_m, x_d,
                                       Wt2, Wz2t, Wrest, bz2, y, out_c, out_m, out_d);

    // K7: aggregate layer 2 + l2norm
    agg_all_k<false, true><<<40000, 256, 0, stream>>>(y, off, csr, out_c, out_m, out_d);
}

// Round 11
// 561.744 us; speedup vs baseline: 1.0519x; 1.0519x over previous
//
#include <hip/hip_runtime.h>
#include <cstdint>
#include <cstddef>

#define EE        800000
#define NC        100000
#define NM        50000
#define ND        10000
#define NSLOTS    320000

// relation order: 0=c->m, 1=m->d, 2=c->d, 3=m->c, 4=d->m, 5=d->c
#define SB0 0
#define SB1 50000
#define SB2 60000
#define SB3 70000
#define SB4 170000
#define SB5 220000

// y_all row offsets per relation (src-transformed tables)
#define R0 0
#define R1 100000
#define R2 150000
#define R3 250000
#define R4 300000
#define R5 310000

// buckets: 400/relation; spb: {125,25,25,250,125,250}
#define NB 2400
#define EPB 4096
#define EBL 196
#define PPB 4096
#define PBL 196
#define BCAP 4096

typedef _Float16 f16x8 __attribute__((ext_vector_type(8)));
typedef float f32x4 __attribute__((ext_vector_type(4)));
typedef float f32x2 __attribute__((ext_vector_type(2)));

__device__ __forceinline__ void bucket_split(int rel, int d, int& lb, int& dl) {
    switch (rel) {
        case 0: case 4: lb = d / 125; dl = d - lb * 125; break;
        case 1: case 2: lb = d / 25;  dl = d - lb * 25;  break;
        default:        lb = d / 250; dl = d - lb * 250; break;
    }
}

__device__ __forceinline__ unsigned f2bf(float f) {   // RNE
    unsigned b = __float_as_uint(f);
    return (b + 0x7FFFu + ((b >> 16) & 1u)) >> 16;
}

// ---- merged: weight prep (blocks 0..191) + bucket hist (blocks 192..1367) ----
// bhist is pre-zeroed by hipMemsetAsync BEFORE this launch (no in-kernel zeroing:
// zero+atomicAdd in one dispatch is a block-order race, learned round 5).
// type order t: 0=m (dst of rels 0,4), 1=d (1,2), 2=c (3,5); rmap {1,2,0}
__global__ __launch_bounds__(256) void cvt_hist_k(
    const float* __restrict__ W1l, const float* __restrict__ W2l,
    const float* __restrict__ W1r, const float* __restrict__ W2r,
    const float* __restrict__ Wres, const float* __restrict__ b1,
    const float* __restrict__ b2, const float* __restrict__ bres,
    _Float16* __restrict__ Wt1, _Float16* __restrict__ Wt2,
    _Float16* __restrict__ Wz1t, _Float16* __restrict__ Wz2t,
    _Float16* __restrict__ Wrest, float* __restrict__ bz1, float* __restrict__ bz2,
    int* __restrict__ bhist,
    const int* __restrict__ d0, const int* __restrict__ d1, const int* __restrict__ d2,
    const int* __restrict__ d3, const int* __restrict__ d4, const int* __restrict__ d5)
{
    __shared__ int hl[400];
    int blk = blockIdx.x;
    int tid = threadIdx.x;
    if (blk < 192) {
        const int raT[3] = {0, 1, 3}, rbT[3] = {4, 2, 5}, rmT[3] = {1, 2, 0};
        int i = blk * 256 + tid;
        if (i < 6 * 128 * 64) {
            int r = i >> 13, rem = i & 8191, k = rem >> 6, n = rem & 63;
            Wt1[(size_t)r * 8192 + (size_t)n * 128 + k] = (_Float16)W1l[i];
        }
        if (i < 6 * 64 * 64) {
            int r = i >> 12, rem = i & 4095, k = rem >> 6, n = rem & 63;
            Wt2[(size_t)r * 4096 + (size_t)n * 64 + k] = (_Float16)W2l[i];
        }
        if (i < 3 * 8192) {
            int t = i >> 13, rem = i & 8191, n = rem >> 7, k = rem & 127;
            float v = 0.5f * (W1r[(size_t)raT[t] * 8192 + k * 64 + n] +
                              W1r[(size_t)rbT[t] * 8192 + k * 64 + n]);
            Wz1t[i] = (_Float16)v;
        }
        if (i < 3 * 4096) {
            int t = i >> 12, rem = i & 4095, n = rem >> 6, k = rem & 63;
            float v = 0.5f * (W2r[(size_t)raT[t] * 4096 + k * 64 + n] +
                              W2r[(size_t)rbT[t] * 4096 + k * 64 + n]);
            Wz2t[i] = (_Float16)v;
        }
        if (i < 3 * 8192) {
            int t = i >> 13, rem = i & 8191, n = rem >> 7, k = rem & 127;
            Wrest[i] = (_Float16)Wres[(size_t)rmT[t] * 8192 + k * 64 + n];
        }
        if (i < 192) {
            int t = i >> 6, n = i & 63;
            bz1[i] = 0.5f * (b1[raT[t] * 64 + n] + b1[rbT[t] * 64 + n]);
            bz2[i] = 0.5f * (b2[raT[t] * 64 + n] + b2[rbT[t] * 64 + n]) + bres[rmT[t] * 64 + n];
        }
        return;
    }
    int hb = blk - 192;
    int rel = hb / EBL;
    int chunk = hb - rel * EBL;
    const int* dst;
    switch (rel) {
        case 0: dst = d0; break; case 1: dst = d1; break; case 2: dst = d2; break;
        case 3: dst = d3; break; case 4: dst = d4; break; default: dst = d5; break;
    }
    for (int i = tid; i < 400; i += 256) hl[i] = 0;
    __syncthreads();
    int e0 = chunk * EPB;
#pragma unroll
    for (int t = 0; t < EPB / 256; ++t) {
        int e = e0 + t * 256 + tid;
        if (e < EE) {
            int lb, dl;
            bucket_split(rel, dst[e], lb, dl);
            atomicAdd(&hl[lb], 1);
        }
    }
    __syncthreads();
    for (int i = tid; i < 400; i += 256) {
        int v = hl[i];
        if (v) atomicAdd(&bhist[rel * 400 + i], v);
    }
}

__global__ __launch_bounds__(256) void bucket_scan_k(const int* __restrict__ bhist,
    int* __restrict__ bOff, int* __restrict__ bCur, int* __restrict__ off)
{
    __shared__ int lds[256];
    int tid = threadIdx.x;
    int v[10];
    int tot = 0;
#pragma unroll
    for (int t = 0; t < 10; ++t) {
        int idx = tid * 10 + t;
        int x = (idx < NB) ? bhist[idx] : 0;
        v[t] = tot;
        tot += x;
    }
    lds[tid] = tot;
    __syncthreads();
    for (int o = 1; o < 256; o <<= 1) {
        int x = 0;
        if (tid >= o) x = lds[tid - o];
        __syncthreads();
        lds[tid] += x;
        __syncthreads();
    }
    int excl = lds[tid] - tot;
#pragma unroll
    for (int t = 0; t < 10; ++t) {
        int idx = tid * 10 + t;
        if (idx < NB) {
            int val = excl + v[t];
            bOff[idx] = val;
            bCur[idx] = val;
        }
    }
    if (tid == 255) {
        bOff[NB] = lds[255];
        off[NSLOTS] = lds[255];
    }
}

// ---- standalone partition (512 threads, 8 dependent-load iters/pass):
// in-LDS counting sort -> coalesced bArr writes (round-8's proven fix for the
// 116 MB partial-line write amplification).
__global__ __launch_bounds__(512) void partition_k(
    const int* __restrict__ s0, const int* __restrict__ d0,
    const int* __restrict__ s1, const int* __restrict__ d1,
    const int* __restrict__ s2, const int* __restrict__ d2,
    const int* __restrict__ s3, const int* __restrict__ d3,
    const int* __restrict__ s4, const int* __restrict__ d4,
    const int* __restrict__ s5, const int* __restrict__ d5,
    int* __restrict__ bCur, int* __restrict__ bArr)
{
    __shared__ int hist[400];                 // counts, then rank counters
    __shared__ int scan_[400];                // exclusive prefix (LDS positions)
    __shared__ int gb[400];                   // global bases
    __shared__ int sorted[PPB];               // payloads, bucket-sorted
    __shared__ unsigned short lbs16[PPB];     // bucket id per sorted pos
    int blk = blockIdx.x;
    int tid = threadIdx.x;
    int rel = blk / PBL;
    int chunk = blk - rel * PBL;
    const int* src; const int* dst;
    switch (rel) {
        case 0: src = s0; dst = d0; break;
        case 1: src = s1; dst = d1; break;
        case 2: src = s2; dst = d2; break;
        case 3: src = s3; dst = d3; break;
        case 4: src = s4; dst = d4; break;
        default: src = s5; dst = d5; break;
    }
    for (int i = tid; i < 400; i += 512) hist[i] = 0;
    __syncthreads();
    int e0 = chunk * PPB;
    int e1 = e0 + PPB; if (e1 > EE) e1 = EE;
    int m = e1 - e0;
    for (int i = tid; i < m; i += 512) {
        int lb, dl;
        bucket_split(rel, dst[e0 + i], lb, dl);
        atomicAdd(&hist[lb], 1);
    }
    __syncthreads();
    // wave 0: exclusive scan over 400 buckets (7 chunks of 64, shfl)
    if (tid < 64) {
        int carry = 0;
#pragma unroll
        for (int c = 0; c < 7; ++c) {
            int idx = c * 64 + tid;
            int orig = (idx < 400) ? hist[idx] : 0;
            int v = orig;
#pragma unroll
            for (int o = 1; o < 64; o <<= 1) {
                int u = __shfl_up(v, o);
                if (tid >= o) v += u;
            }
            if (idx < 400) scan_[idx] = carry + v - orig;
            carry += __shfl(v, 63);
        }
    }
    // concurrently: per-bucket global reservation (reads hist only)
    for (int i = tid; i < 400; i += 512) {
        int c = hist[i];
        gb[i] = c ? atomicAdd(&bCur[rel * 400 + i], c) : 0;
    }
    __syncthreads();
    for (int i = tid; i < 400; i += 512) hist[i] = 0;   // rank counters
    __syncthreads();
    for (int i = tid; i < m; i += 512) {
        int d = dst[e0 + i];          // L2-hot re-read
        int s = src[e0 + i];
        int lb, dl;
        bucket_split(rel, d, lb, dl);
        int r = atomicAdd(&hist[lb], 1);
        int pos = scan_[lb] + r;
        sorted[pos] = (dl << 17) | s;
        lbs16[pos] = (unsigned short)lb;
    }
    __syncthreads();
    // coalesced write-out: consecutive i -> consecutive global addresses
    for (int i = tid; i < m; i += 512) {
        int lb = lbs16[i];
        bArr[gb[lb] + i - scan_[lb]] = sorted[i];
    }
}

// ---- merged: bucket_build (blocks 0..2399) + fused L1 (blocks 2400..4901) ----
// build and fused1 are data-independent; union LDS 19.5 KB -> 8 blocks/CU.
// csr payload = src byte-offset (src<<7).  bArr ALIASES csr: whole bucket
// (<= BCAP; stat max ~2225) staged into LDS before any csr write.
__global__ __launch_bounds__(256) void build_fused1_k(
    const int* __restrict__ bArr, const int* __restrict__ bOff,
    int* __restrict__ off, int* __restrict__ csr,
    const float* __restrict__ fc, const float* __restrict__ fm, const float* __restrict__ fd,
    const _Float16* __restrict__ Wt1, const _Float16* __restrict__ Wz1t,
    const float* __restrict__ bz1,
    unsigned short* __restrict__ y,
    float* __restrict__ hc, float* __restrict__ hm, float* __restrict__ hd)
{
    __shared__ __align__(16) char smem[19456];
    int blk = blockIdx.x;
    int tid = threadIdx.x;
    if (blk < NB) {
        int* cnt = (int*)smem;            // 256
        int* sc = cnt + 256;              // 256
        int* cur = sc + 256;              // 256
        int* stage = cur + 256;           // 4096
        int b = blk;
        int r = b / 400;
        int lb = b - r * 400;
        int spb, sbase;
        switch (r) {
            case 0: spb = 125; sbase = SB0; break;
            case 1: spb = 25;  sbase = SB1; break;
            case 2: spb = 25;  sbase = SB2; break;
            case 3: spb = 250; sbase = SB3; break;
            case 4: spb = 125; sbase = SB4; break;
            default: spb = 250; sbase = SB5; break;
        }
        int slot0 = lb * spb;
        int e0 = bOff[b], e1 = bOff[b + 1];
        int m = e1 - e0;
        int ms = m < BCAP ? m : BCAP;

        cnt[tid] = 0;
        __syncthreads();
        for (int i = tid; i < ms; i += 256) {
            int p = bArr[e0 + i];
            stage[i] = p;
            atomicAdd(&cnt[p >> 17], 1);
        }
        __syncthreads();
        int x = cnt[tid];
        sc[tid] = x;
        __syncthreads();
        for (int o = 1; o < 256; o <<= 1) {
            int yv = 0;
            if (tid >= o) yv = sc[tid - o];
            __syncthreads();
            sc[tid] += yv;
            __syncthreads();
        }
        int excl = sc[tid] - x;
        cur[tid] = excl;
        if (tid < spb) off[sbase + slot0 + tid] = e0 + excl;
        __syncthreads();
        for (int i = tid; i < ms; i += 256) {
            int p = stage[i];
            int pos = atomicAdd(&cur[p >> 17], 1);
            csr[e0 + pos] = (p & 0x1FFFF) << 7;
        }
        return;
    }
    // ---- fused1: per 64-row tile of type t, stage x once (f16, LDS):
    //   wave0: y[ra]=x@Wt1[ra]  wave1: y[rb]=x@Wt1[rb]  wave2/3: h=x@Wz1t[t]+bz1[t]
    _Float16* xs = (_Float16*)smem;   // [64][136]
    int b = blk - NB;
    int t, lb;
    if (b < 782)      { t = 0; lb = b; }
    else if (b < 939) { t = 1; lb = b - 782; }
    else              { t = 2; lb = b - 939; }
    const float* x; int n; float* zo; int ra, rb, roA, roB;
    switch (t) {
        case 0: x = fm; n = NM; zo = hm; ra = 1; rb = 3; roA = R1; roB = R3; break;
        case 1: x = fd; n = ND; zo = hd; ra = 4; rb = 5; roA = R4; roB = R5; break;
        default: x = fc; n = NC; zo = hc; ra = 0; rb = 2; roA = R0; roB = R2; break;
    }
    int node0 = lb * 64;
    for (int idx = tid; idx < 64 * 16; idx += 256) {
        int nn = idx >> 4, c8 = idx & 15;
        int g = node0 + nn;
        float4 u0 = make_float4(0.f, 0.f, 0.f, 0.f), u1 = u0;
        if (g < n) {
            const float4* p = (const float4*)(x + (size_t)g * 128 + c8 * 8);
            u0 = p[0]; u1 = p[1];
        }
        f16x8 v;
        v[0] = (_Float16)u0.x; v[1] = (_Float16)u0.y; v[2] = (_Float16)u0.z; v[3] = (_Float16)u0.w;
        v[4] = (_Float16)u1.x; v[5] = (_Float16)u1.y; v[6] = (_Float16)u1.z; v[7] = (_Float16)u1.w;
        *(f16x8*)(xs + nn * 136 + c8 * 8) = v;
    }
    __syncthreads();
    int lane = tid & 63, wv = tid >> 6;
    int lr = lane & 15, lg = lane >> 4;
    if (wv < 2) {
        int rel = wv ? rb : ra;
        int ro  = wv ? roB : roA;
        const _Float16* W = Wt1 + (size_t)rel * 8192;
        unsigned short* yo = y + (size_t)ro * 64;
        f16x8 bf[4][4];
#pragma unroll
        for (int kt = 0; kt < 4; ++kt)
#pragma unroll
            for (int nt = 0; nt < 4; ++nt)
                bf[kt][nt] = *(const f16x8*)(W + (size_t)(nt * 16 + lr) * 128 + kt * 32 + lg * 8);
#pragma unroll
        for (int rt = 0; rt < 4; ++rt) {
            f32x4 acc[4];
#pragma unroll
            for (int nt = 0; nt < 4; ++nt) { acc[nt][0] = 0.f; acc[nt][1] = 0.f; acc[nt][2] = 0.f; acc[nt][3] = 0.f; }
            const _Float16* xrow = xs + (rt * 16 + lr) * 136;
#pragma unroll
            for (int kt = 0; kt < 4; ++kt) {
                f16x8 af = *(const f16x8*)(xrow + kt * 32 + lg * 8);
#pragma unroll
                for (int nt = 0; nt < 4; ++nt)
                    acc[nt] = __builtin_amdgcn_mfma_f32_16x16x32_f16(af, bf[kt][nt], acc[nt], 0, 0, 0);
            }
            int orow = node0 + rt * 16 + lg * 4;
#pragma unroll
            for (int rg = 0; rg < 4; ++rg) {
                int gg = orow + rg;
                if (gg < n) {
                    unsigned short* yr = yo + (size_t)gg * 64 + lr;
#pragma unroll
                    for (int nt = 0; nt < 4; ++nt)
                        yr[nt * 16] = (unsigned short)f2bf(acc[nt][rg]);
                }
            }
        }
    } else {
        const _Float16* W = Wz1t + (size_t)t * 8192;
        const float* bz = bz1 + t * 64;
        f16x8 bf[4][4];
#pragma unroll
        for (int kt = 0; kt < 4; ++kt)
#pragma unroll
            for (int nt = 0; nt < 4; ++nt)
                bf[kt][nt] = *(const f16x8*)(W + (size_t)(nt * 16 + lr) * 128 + kt * 32 + lg * 8);
        int rbase = (wv - 2) * 32;
#pragma unroll
        for (int rt = 0; rt < 2; ++rt) {
            f32x4 acc[4];
#pragma unroll
            for (int nt = 0; nt < 4; ++nt) {
                float bv = bz[nt * 16 + lr];
                acc[nt][0] = bv; acc[nt][1] = bv; acc[nt][2] = bv; acc[nt][3] = bv;
            }
            const _Float16* xrow = xs + (rbase + rt * 16 + lr) * 136;
#pragma unroll
            for (int kt = 0; kt < 4; ++kt) {
                f16x8 af = *(const f16x8*)(xrow + kt * 32 + lg * 8);
#pragma unroll
                for (int nt = 0; nt < 4; ++nt)
                    acc[nt] = __builtin_amdgcn_mfma_f32_16x16x32_f16(af, bf[kt][nt], acc[nt], 0, 0, 0);
            }
            int orow = node0 + rbase + rt * 16 + lg * 4;
#pragma unroll
            for (int rg = 0; rg < 4; ++rg) {
                int gg = orow + rg;
                if (gg < n) {
                    float* zr = zo + (size_t)gg * 64 + lr;
#pragma unroll
                    for (int nt = 0; nt < 4; ++nt)
                        zr[nt * 16] = acc[nt][rg];
                }
            }
        }
    }
}

// ---- fused L2: per 64-row tile of type t, stage h + x once (f16, LDS):
//   wave0: y[ra] = h@Wt2[ra]   wave1: y[rb] = h@Wt2[rb]
//   wave2/3: out = h@Wz2t[t] + x@Wrest[t] + bz2[t]
__global__ __launch_bounds__(256) void fused2_k(
    const float* __restrict__ hc, const float* __restrict__ hm, const float* __restrict__ hd,
    const float* __restrict__ xc, const float* __restrict__ xm, const float* __restrict__ xd,
    const _Float16* __restrict__ Wt2, const _Float16* __restrict__ Wz2t,
    const _Float16* __restrict__ Wrest, const float* __restrict__ bz2,
    unsigned short* __restrict__ y,
    float* __restrict__ oc, float* __restrict__ om, float* __restrict__ od)
{
    int b = blockIdx.x;
    int t, lb;
    if (b < 782)      { t = 0; lb = b; }
    else if (b < 939) { t = 1; lb = b - 782; }
    else              { t = 2; lb = b - 939; }
    const float *h, *x; int n; float* zo; int ra, rb, roA, roB;
    switch (t) {
        case 0: h = hm; x = xm; n = NM; zo = om; ra = 1; rb = 3; roA = R1; roB = R3; break;
        case 1: h = hd; x = xd; n = ND; zo = od; ra = 4; rb = 5; roA = R4; roB = R5; break;
        default: h = hc; x = xc; n = NC; zo = oc; ra = 0; rb = 2; roA = R0; roB = R2; break;
    }
    __shared__ _Float16 hs[64 * 72];
    __shared__ _Float16 xs[64 * 136];
    int tid = threadIdx.x;
    int node0 = lb * 64;
    for (int idx = tid; idx < 64 * 8; idx += 256) {
        int nn = idx >> 3, c8 = idx & 7;
        int g = node0 + nn;
        float4 u0 = make_float4(0.f, 0.f, 0.f, 0.f), u1 = u0;
        if (g < n) {
            const float4* p = (const float4*)(h + (size_t)g * 64 + c8 * 8);
            u0 = p[0]; u1 = p[1];
        }
        f16x8 v;
        v[0] = (_Float16)u0.x; v[1] = (_Float16)u0.y; v[2] = (_Float16)u0.z; v[3] = (_Float16)u0.w;
        v[4] = (_Float16)u1.x; v[5] = (_Float16)u1.y; v[6] = (_Float16)u1.z; v[7] = (_Float16)u1.w;
        *(f16x8*)(hs + nn * 72 + c8 * 8) = v;
    }
    for (int idx = tid; idx < 64 * 16; idx += 256) {
        int nn = idx >> 4, c8 = idx & 15;
        int g = node0 + nn;
        float4 u0 = make_float4(0.f, 0.f, 0.f, 0.f), u1 = u0;
        if (g < n) {
            const float4* p = (const float4*)(x + (size_t)g * 128 + c8 * 8);
            u0 = p[0]; u1 = p[1];
        }
        f16x8 v;
        v[0] = (_Float16)u0.x; v[1] = (_Float16)u0.y; v[2] = (_Float16)u0.z; v[3] = (_Float16)u0.w;
        v[4] = (_Float16)u1.x; v[5] = (_Float16)u1.y; v[6] = (_Float16)u1.z; v[7] = (_Float16)u1.w;
        *(f16x8*)(xs + nn * 136 + c8 * 8) = v;
    }
    __syncthreads();
    int lane = tid & 63, wv = tid >> 6;
    int lr = lane & 15, lg = lane >> 4;
    if (wv < 2) {
        int rel = wv ? rb : ra;
        int ro  = wv ? roB : roA;
        const _Float16* W = Wt2 + (size_t)rel * 4096;
        unsigned short* yo = y + (size_t)ro * 64;
        f16x8 bf[2][4];
#pragma unroll
        for (int kt = 0; kt < 2; ++kt)
#pragma unroll
            for (int nt = 0; nt < 4; ++nt)
                bf[kt][nt] = *(const f16x8*)(W + (size_t)(nt * 16 + lr) * 64 + kt * 32 + lg * 8);
#pragma unroll
        for (int rt = 0; rt < 4; ++rt) {
            f32x4 acc[4];
#pragma unroll
            for (int nt = 0; nt < 4; ++nt) { acc[nt][0] = 0.f; acc[nt][1] = 0.f; acc[nt][2] = 0.f; acc[nt][3] = 0.f; }
            const _Float16* hrow = hs + (rt * 16 + lr) * 72;
#pragma unroll
            for (int kt = 0; kt < 2; ++kt) {
                f16x8 af = *(const f16x8*)(hrow + kt * 32 + lg * 8);
#pragma unroll
                for (int nt = 0; nt < 4; ++nt)
                    acc[nt] = __builtin_amdgcn_mfma_f32_16x16x32_f16(af, bf[kt][nt], acc[nt], 0, 0, 0);
            }
            int orow = node0 + rt * 16 + lg * 4;
#pragma unroll
            for (int rg = 0; rg < 4; ++rg) {
                int gg = orow + rg;
                if (gg < n) {
                    unsigned short* yr = yo + (size_t)gg * 64 + lr;
#pragma unroll
                    for (int nt = 0; nt < 4; ++nt)
                        yr[nt * 16] = (unsigned short)f2bf(acc[nt][rg]);
                }
            }
        }
    } else {
        const _Float16* Wh = Wz2t + (size_t)t * 4096;
        const _Float16* Wx = Wrest + (size_t)t * 8192;
        const float* bz = bz2 + t * 64;
        f16x8 bfh[2][4];
#pragma unroll
        for (int kt = 0; kt < 2; ++kt)
#pragma unroll
            for (int nt = 0; nt < 4; ++nt)
                bfh[kt][nt] = *(const f16x8*)(Wh + (size_t)(nt * 16 + lr) * 64 + kt * 32 + lg * 8);
        f16x8 bfx[4][4];
#pragma unroll
        for (int kt = 0; kt < 4; ++kt)
#pragma unroll
            for (int nt = 0; nt < 4; ++nt)
                bfx[kt][nt] = *(const f16x8*)(Wx + (size_t)(nt * 16 + lr) * 128 + kt * 32 + lg * 8);
        int rbase = (wv - 2) * 32;
#pragma unroll
        for (int rt = 0; rt < 2; ++rt) {
            f32x4 acc[4];
#pragma unroll
            for (int nt = 0; nt < 4; ++nt) {
                float bv = bz[nt * 16 + lr];
                acc[nt][0] = bv; acc[nt][1] = bv; acc[nt][2] = bv; acc[nt][3] = bv;
            }
            const _Float16* hrow = hs + (rbase + rt * 16 + lr) * 72;
            const _Float16* xrow = xs + (rbase + rt * 16 + lr) * 136;
#pragma unroll
            for (int kt = 0; kt < 2; ++kt) {
                f16x8 af = *(const f16x8*)(hrow + kt * 32 + lg * 8);
#pragma unroll
                for (int nt = 0; nt < 4; ++nt)
                    acc[nt] = __builtin_amdgcn_mfma_f32_16x16x32_f16(af, bfh[kt][nt], acc[nt], 0, 0, 0);
            }
#pragma unroll
            for (int kt = 0; kt < 4; ++kt) {
                f16x8 af = *(const f16x8*)(xrow + kt * 32 + lg * 8);
#pragma unroll
                for (int nt = 0; nt < 4; ++nt)
                    acc[nt] = __builtin_amdgcn_mfma_f32_16x16x32_f16(af, bfx[kt][nt], acc[nt], 0, 0, 0);
            }
            int orow = node0 + rbase + rt * 16 + lg * 4;
#pragma unroll
            for (int rg = 0; rg < 4; ++rg) {
                int gg = orow + rg;
                if (gg < n) {
                    float* zr = zo + (size_t)gg * 64 + lr;
#pragma unroll
                    for (int nt = 0; nt < 4; ++nt)
                        zr[nt * 16] = acc[nt][rg];
                }
            }
        }
    }
}

// packed bf16x8 fused accumulate: 8 cvt ops + 4 v_pk_fma_f32 (scale s folded in)
__device__ __forceinline__ void acc_fma(f32x2* a, uint4 v, float s) {
    f32x2 sv; sv[0] = s; sv[1] = s;
    f32x2 t0, t1, t2, t3;
    t0[0] = __uint_as_float(v.x << 16); t0[1] = __uint_as_float(v.x & 0xFFFF0000u);
    t1[0] = __uint_as_float(v.y << 16); t1[1] = __uint_as_float(v.y & 0xFFFF0000u);
    t2[0] = __uint_as_float(v.z << 16); t2[1] = __uint_as_float(v.z & 0xFFFF0000u);
    t3[0] = __uint_as_float(v.w << 16); t3[1] = __uint_as_float(v.w & 0xFFFF0000u);
    a[0] += t0 * sv; a[1] += t1 * sv; a[2] += t2 * sv; a[3] += t3 * sv;
}

// fused aggregate (bf16 y, csr = byte offsets):
//   io[wid] = post(0.5*(mean(y1[csr])+mean(y2[csr])) + io[wid])
// round-11: 8 groups x 8 lanes, uint4 loads (round-9 geometry — round-10's 8-B
// loads halved bytes/load-instruction and regressed). NEW: the two relation
// edge lists are fused into ONE virtual stream so their row-loads overlap —
// low-degree destinations (c: 1 edge/group/rel) previously paid two sequential
// full latencies; now both rows are in flight together. Per-row scale via
// pk_fma with segment-selected inv keeps a single accumulator array.
template<bool RELU, bool NORM>
__global__ __launch_bounds__(256) void agg_all_k(
    const unsigned short* __restrict__ y, const int* __restrict__ off,
    const int* __restrict__ csr,
    float* __restrict__ ioc, float* __restrict__ iom, float* __restrict__ iod)
{
    int w = blockIdx.x * 4 + (threadIdx.x >> 6);
    int t, wid;
    if (w < NM) { t = 0; wid = w; }
    else if (w < NM + ND) { t = 1; wid = w - NM; }
    else { t = 2; wid = w - NM - ND; }
    const int *o1, *o2; const unsigned short *y1, *y2; float* io;
    switch (t) {
        case 0: o1 = off + SB0; o2 = off + SB4; y1 = y + (size_t)R0 * 64; y2 = y + (size_t)R4 * 64; io = iom; break;
        case 1: o1 = off + SB1; o2 = off + SB2; y1 = y + (size_t)R1 * 64; y2 = y + (size_t)R2 * 64; io = iod; break;
        default: o1 = off + SB3; o2 = off + SB5; y1 = y + (size_t)R3 * 64; y2 = y + (size_t)R5 * 64; io = ioc; break;
    }
    int lane = threadIdx.x & 63;
    int g = lane >> 3, ql = lane & 7;   // group, quarter-lane
    int qoff = ql * 16;
    const char* ybA = (const char*)y1 + qoff;
    const char* ybB = (const char*)y2 + qoff;
    int e0A = o1[wid], e1A = o1[wid + 1];
    int e0B = o2[wid], e1B = o2[wid + 1];
    int nA = e1A - e0A, nB = e1B - e0B;
    int n = nA + nB;
    float invA = 1.f / fmaxf((float)nA, 1.f);
    float invB = 1.f / fmaxf((float)nB, 1.f);
    int dB = e0B - nA;   // virtual pos k: csr idx = (k<nA ? e0A : dB) + k

    f32x2 acc[4];
#pragma unroll
    for (int j = 0; j < 4; ++j) { acc[j][0] = 0.f; acc[j][1] = 0.f; }

    int k = g;
    int i0 = 0, i1 = 0;
    bool b0 = false, b1 = false;
    if (k < n)     { b0 = k >= nA;     i0 = csr[(b0 ? dB : e0A) + k]; }
    if (k + 8 < n) { b1 = k + 8 >= nA; i1 = csr[(b1 ? dB : e0A) + k + 8]; }
    for (; k + 8 < n; k += 16) {
        bool nb0 = (k + 16) >= nA, nb1 = (k + 24) >= nA;
        int p0 = csr[(nb0 ? dB : e0A) + k + 16];   // unclamped prefetch (ws slack)
        int p1 = csr[(nb1 ? dB : e0A) + k + 24];
        uint4 v0 = *(const uint4*)((b0 ? ybB : ybA) + (unsigned)i0);
        uint4 v1 = *(const uint4*)((b1 ? ybB : ybA) + (unsigned)i1);
        acc_fma(acc, v0, b0 ? invB : invA);
        acc_fma(acc, v1, b1 ? invB : invA);
        i0 = p0; i1 = p1; b0 = nb0; b1 = nb1;
    }
    if (k < n) {
        uint4 v = *(const uint4*)((b0 ? ybB : ybA) + (unsigned)i0);
        acc_fma(acc, v, b0 ? invB : invA);
    }
    // reduce across the 8 groups (component-wise)
#pragma unroll
    for (int j = 0; j < 4; ++j) {
#pragma unroll
        for (int c = 0; c < 2; ++c) {
            float v = acc[j][c];
            v += __shfl_xor(v, 8);
            v += __shfl_xor(v, 16);
            v += __shfl_xor(v, 32);
            acc[j][c] = v;
        }
    }
    if (g == 0) {
        float* iorow = io + ((size_t)wid << 6) + ql * 8;
        float4 z1 = *((const float4*)iorow);
        float4 z2 = *((const float4*)(iorow + 4));
        float o[8];
        o[0] = 0.5f * acc[0][0] + z1.x; o[1] = 0.5f * acc[0][1] + z1.y;
        o[2] = 0.5f * acc[1][0] + z1.z; o[3] = 0.5f * acc[1][1] + z1.w;
        o[4] = 0.5f * acc[2][0] + z2.x; o[5] = 0.5f * acc[2][1] + z2.y;
        o[6] = 0.5f * acc[3][0] + z2.z; o[7] = 0.5f * acc[3][1] + z2.w;
        if (RELU) {
#pragma unroll
            for (int j = 0; j < 8; ++j) o[j] = fmaxf(o[j], 0.f);
        }
        if (NORM) {
            float ss = 0.f;
#pragma unroll
            for (int j = 0; j < 8; ++j) ss += o[j] * o[j];
            ss += __shfl_xor(ss, 1); ss += __shfl_xor(ss, 2); ss += __shfl_xor(ss, 4);
            float r = 1.f / fmaxf(sqrtf(ss), 1e-12f);
#pragma unroll
            for (int j = 0; j < 8; ++j) o[j] *= r;
        }
        *((float4*)iorow) = make_float4(o[0], o[1], o[2], o[3]);
        *((float4*)(iorow + 4)) = make_float4(o[4], o[5], o[6], o[7]);
    }
}

extern "C" void kernel_launch(void* const* d_in, const int* in_sizes, int n_in,
                              void* d_out, int out_size, void* d_ws, size_t ws_size,
                              hipStream_t stream) {
    const float* x_c = (const float*)d_in[0];
    const float* x_m = (const float*)d_in[1];
    const float* x_d = (const float*)d_in[2];
    const int* src_cm = (const int*)d_in[3];
    const int* dst_cm = (const int*)d_in[4];
    const int* src_md = (const int*)d_in[5];
    const int* dst_md = (const int*)d_in[6];
    const int* src_cd = (const int*)d_in[7];
    const int* dst_cd = (const int*)d_in[8];
    const int* src_mc = (const int*)d_in[9];
    const int* dst_mc = (const int*)d_in[10];
    const int* src_dm = (const int*)d_in[11];
    const int* dst_dm = (const int*)d_in[12];
    const int* src_dc = (const int*)d_in[13];
    const int* dst_dc = (const int*)d_in[14];
    const float* W1l = (const float*)d_in[15];  // [6][128][64]
    const float* W1r = (const float*)d_in[16];
    const float* b1 = (const float*)d_in[17];   // [6][64]
    const float* W2l = (const float*)d_in[18];  // [6][64][64]
    const float* W2r = (const float*)d_in[19];
    const float* b2 = (const float*)d_in[20];
    const float* Wres = (const float*)d_in[21]; // [3][128][64]
    const float* bres = (const float*)d_in[22]; // [3][64]
    float* out = (float*)d_out;

    // workspace
    int* off = (int*)d_ws;                 // 320064
    int* csr = off + 320064;               // 4,800,000 (+slack reads OK)
    int* bArr = csr;                       // ALIAS: build stages whole bucket in LDS
    int* bhist = csr + 4800000;            // 2400
    int* bOff = bhist + 2400;              // 2404
    int* bCur = bOff + 2404;               // 2404
    float* h = (float*)(bCur + 2404);      // 160000*64 floats: [c|m|d]
    float* h_c = h;
    float* h_m = h_c + (size_t)NC * 64;
    float* h_d = h_m + (size_t)NM * 64;
    unsigned short* y = (unsigned short*)(h + (size_t)160000 * 64); // 320000*64 bf16
    _Float16* Wt1 = (_Float16*)(y + (size_t)320000 * 64);  // 6*64*128 f16
    _Float16* Wt2 = Wt1 + 6 * 64 * 128;                    // 6*64*64 f16
    _Float16* Wz1t = Wt2 + 6 * 64 * 64;                    // 3*64*128
    _Float16* Wz2t = Wz1t + 3 * 64 * 128;                  // 3*64*64
    _Float16* Wrest = Wz2t + 3 * 64 * 64;                  // 3*64*128
    float* bz1 = (float*)(Wrest + 3 * 64 * 128);           // 3*64
    float* bz2 = bz1 + 192;                                // 3*64

    float* out_c = out;
    float* out_m = out + (size_t)NC * 64;
    float* out_d = out_m + (size_t)NM * 64;

    // K0: zero bhist (stream-ordered BEFORE the hist kernel — block-order-safe)
    hipMemsetAsync(bhist, 0, NB * sizeof(int), stream);

    // K1: weight prep + bucket hist (independent, one launch)
    cvt_hist_k<<<192 + EBL * 6, 256, 0, stream>>>(
        W1l, W2l, W1r, W2r, Wres, b1, b2, bres,
        Wt1, Wt2, Wz1t, Wz2t, Wrest, bz1, bz2, bhist,
        dst_cm, dst_md, dst_cd, dst_mc, dst_dm, dst_dc);

    // K2: bucket scan
    bucket_scan_k<<<1, 256, 0, stream>>>(bhist, bOff, bCur, off);

    // K3: partition (512 thr, counting-sorted coalesced writes)
    partition_k<<<6 * PBL, 512, 0, stream>>>(
        src_cm, dst_cm, src_md, dst_md, src_cd, dst_cd,
        src_mc, dst_mc, src_dm, dst_dm, src_dc, dst_dc,
        bCur, bArr);

    // K4: bucket_build (2400 blocks, first) overlapped with fused L1 (2502 blocks)
    build_fused1_k<<<NB + 2502, 256, 0, stream>>>(
        bArr, bOff, off, csr,
        x_c, x_m, x_d, Wt1, Wz1t, bz1, y, h_c, h_m, h_d);

    // K5: aggregate layer 1
    agg_all_k<true, false><<<40000, 256, 0, stream>>>(y, off, csr, h_c, h_m, h_d);

    // K6: fused L2 GEMMs
    fused2_k<<<2502, 256, 0, stream>>>(h_c, h_m, h_d, x_c, x_m, x_d,
                                       Wt2, Wz2t, Wrest, bz2, y, out_c, out_m, out_d);

    // K7: aggregate layer 2 + l2norm
    agg_all_k<false, true><<<40000, 256, 0, stream>>>(y, off, csr, out_c, out_m, out_d);
}